// Round 3
// baseline (1999.816 us; speedup 1.0000x reference)
//
#include <hip/hip_runtime.h>

#define NN 20000
#define NE 200000
#define NG 512

__device__ __forceinline__ int lowerb(const int* a, int n, int v){
  int lo=0, hi=n;
  while(lo<hi){ int m=(lo+hi)>>1; if(a[m]<v) lo=m+1; else hi=m; }
  return lo;
}

// ---------------- counting sort by tgt -> CSR ----------------
__global__ void k_count(const int* __restrict__ tgt, int* __restrict__ cnt){
  int e = blockIdx.x*blockDim.x + threadIdx.x;
  if(e<NE) atomicAdd(&cnt[tgt[e]], 1);
}

__global__ void k_scan(const int* __restrict__ cnt, int* __restrict__ row_start){
  __shared__ int part[1024];
  int t = threadIdx.x;
  const int CH = (NN + 1023)/1024; // 20
  int i0 = t*CH;
  int s = 0;
  for(int j=0;j<CH;j++){ int i=i0+j; if(i<NN) s += cnt[i]; }
  part[t] = s; __syncthreads();
  for(int d=1; d<1024; d<<=1){
    int v = (t>=d) ? part[t-d] : 0;
    __syncthreads();
    part[t] += v;
    __syncthreads();
  }
  int run = (t==0) ? 0 : part[t-1];
  for(int j=0;j<CH;j++){ int i=i0+j; if(i<NN){ row_start[i]=run; run += cnt[i]; } }
  if(t==0) row_start[NN] = part[1023];
}

__global__ void k_place(const int* __restrict__ src, const int* __restrict__ tgt,
                        const int* __restrict__ row_start, int* __restrict__ cur,
                        int* __restrict__ es_src, int* __restrict__ es_pos){
  int e = blockIdx.x*blockDim.x + threadIdx.x;
  if(e>=NE) return;
  int n = tgt[e];
  int pos = row_start[n] + atomicAdd(&cur[n],1);
  es_src[pos] = src[e];
  es_pos[e] = pos;
}

__global__ void k_gatherea(const float* __restrict__ ea, const int* __restrict__ es_pos,
                           float* __restrict__ es_ea){
  int e = blockIdx.x*blockDim.x + threadIdx.x;
  if(e>=NE) return;
  int p = es_pos[e];
  const float4* s = (const float4*)ea + (size_t)e*4;
  float4* d = (float4*)es_ea + (size_t)p*4;
  d[0]=s[0]; d[1]=s[1]; d[2]=s[2]; d[3]=s[3];
}

// gather x into CSR edge order: xg[pos] = x[es_src[pos]]
template<int IC>
__global__ void k_gatherx(const float* __restrict__ x, const int* __restrict__ es_src,
                          float* __restrict__ xg){
  constexpr int QV = IC/4;
  int idx = blockIdx.x*256 + threadIdx.x;
  if(idx >= NE*QV) return;
  int pos = idx/QV, q = idx - pos*QV;
  ((float4*)xg)[idx] = ((const float4*)x)[(size_t)es_src[pos]*QV + q];
}

// ---------------- H = relu(es_ea @ W1 + b1), CSR-ordered, E x 128 ----------------
// thread = (pc: 32 p-chunks of 4) x (er: 8 edges/block); W1 column-slice in registers
__launch_bounds__(256, 4)
__global__ void k_hmlp(const float* __restrict__ es_ea, const float* __restrict__ W1,
                       const float* __restrict__ b1, float* __restrict__ H){
  const int pc = threadIdx.x & 31, er = threadIdx.x >> 5;
  const size_t e = (size_t)blockIdx.x*8 + er;
  float4 w1v[16];
  #pragma unroll
  for(int i=0;i<16;i++) w1v[i] = *(const float4*)&W1[i*128 + pc*4];
  float4 hv = *(const float4*)&b1[pc*4];
  float eav[16];
  const float4* eap = (const float4*)(es_ea + e*16);
  #pragma unroll
  for(int q=0;q<4;q++){
    float4 v = eap[q];
    eav[q*4+0]=v.x; eav[q*4+1]=v.y; eav[q*4+2]=v.z; eav[q*4+3]=v.w;
  }
  #pragma unroll
  for(int i=0;i<16;i++){
    hv.x += eav[i]*w1v[i].x;
    hv.y += eav[i]*w1v[i].y;
    hv.z += eav[i]*w1v[i].z;
    hv.w += eav[i]*w1v[i].w;
  }
  hv.x = fmaxf(hv.x,0.f); hv.y = fmaxf(hv.y,0.f);
  hv.z = fmaxf(hv.z,0.f); hv.w = fmaxf(hv.w,0.f);
  *(float4*)&H[e*128 + pc*4] = hv;
}

// ---------------- fused NNConv layer: register scatter + wave-private GEMM ----------------
// PLEN=32 (KS=4). Wave owns G=BN/4 nodes. Lane = (pt:4, it:16).
// scatter: acc[g][p(8)][u(TI)] += H[e, p0+pt*8+p] * xg[e, it*TI+u]  (global loads only)
// then scale by 1/deg, dump to wave-private LDS S rows, GEMM vs W2 (lanes kc16 x og4),
// shuffle-reduce over kc, store part[split].
template<int IC, int OC, int KS, int BN, int MINW>
__launch_bounds__(256, MINW)
__global__ void k_layer(const float* __restrict__ xg, const float* __restrict__ H,
                        const int* __restrict__ row_start,
                        const float* __restrict__ W2, const float* __restrict__ b2,
                        float* __restrict__ part)
{
  constexpr int G  = BN/4;
  constexpr int TI = IC/16;
  constexpr int K  = 32*IC;
  constexpr int OT = OC/4;
  constexpr int ITERS = K/64;

  __shared__ __align__(16) float S[BN*K];
  __shared__ float xbs[BN*IC];

  const int tid = threadIdx.x;
  const int wid = tid>>6, lane = tid&63;
  const int pt = lane>>4, it = lane&15;
  const int split = blockIdx.x % KS;
  const int nb = blockIdx.x / KS;
  const int nodeBase = nb*BN + wid*G;
  const int p0 = split*32;

  float acc[G][8][TI];
  float xsum[G][TI];
  float dinv_r[G];
  #pragma unroll
  for(int g=0;g<G;g++){
    #pragma unroll
    for(int p=0;p<8;p++)
      #pragma unroll
      for(int u=0;u<TI;u++) acc[g][p][u]=0.f;
    #pragma unroll
    for(int u=0;u<TI;u++) xsum[g][u]=0.f;
  }

  // ---- scatter (no LDS, no barrier) ----
  #pragma unroll
  for(int g=0; g<G; g++){
    const int n = nodeBase+g;
    const int a = row_start[n], b = row_start[n+1];
    dinv_r[g] = 1.f/fmaxf((float)(b-a),1.f);
    if(a>=b) continue;
    const float* Hp = H + (size_t)a*128 + p0 + pt*8;
    const float* Xp = xg + (size_t)a*IC + it*TI;
    float4 c0 = *(const float4*)Hp;
    float4 c1 = *(const float4*)(Hp+4);
    float xv[TI];
    #pragma unroll
    for(int u=0;u<TI;u++) xv[u]=Xp[u];
    for(int e=a; e<b; e++){
      float4 d0, d1; float nx[TI];
      if(e+1<b){
        Hp += 128; Xp += IC;
        d0 = *(const float4*)Hp; d1 = *(const float4*)(Hp+4);
        #pragma unroll
        for(int u=0;u<TI;u++) nx[u]=Xp[u];
      }
      float hv[8] = {c0.x,c0.y,c0.z,c0.w,c1.x,c1.y,c1.z,c1.w};
      #pragma unroll
      for(int u=0;u<TI;u++){
        float xe = xv[u];
        xsum[g][u] += xe;
        #pragma unroll
        for(int p=0;p<8;p++) acc[g][p][u] += hv[p]*xe;
      }
      c0=d0; c1=d1;
      #pragma unroll
      for(int u=0;u<TI;u++) xv[u]=nx[u];
    }
  }

  // ---- dump scaled S + xbar to wave-private LDS ----
  #pragma unroll
  for(int g=0; g<G; g++){
    const float dv = dinv_r[g];
    float* Sp = &S[(size_t)(wid*G+g)*K + (pt*8)*IC + it*TI];
    #pragma unroll
    for(int p=0;p<8;p++)
      #pragma unroll
      for(int u=0;u<TI;u++) Sp[p*IC+u] = acc[g][p][u]*dv;
    if(pt==0){
      #pragma unroll
      for(int u=0;u<TI;u++) xbs[(wid*G+g)*IC + it*TI + u] = xsum[g][u]*dv;
    }
  }

  // ---- wave-private GEMM vs W2 ----
  const int kc = lane&15, og = lane>>4;
  const int o0 = og*OT;
  float accg[G][OT];
  #pragma unroll
  for(int g=0;g<G;g++)
    #pragma unroll
    for(int t=0;t<OT;t++) accg[g][t]=0.f;
  const float* W2p = W2 + (size_t)p0*IC*OC + o0;
  for(int itr=0; itr<ITERS; itr++){
    const int k = 4*(kc + 16*itr);
    float4 sv[G];
    #pragma unroll
    for(int g=0;g<G;g++) sv[g] = *(const float4*)&S[(size_t)(wid*G+g)*K + k];
    #pragma unroll
    for(int r=0;r<4;r++){
      float w[OT];
      #pragma unroll
      for(int t4=0;t4<OT/4;t4++)
        *(float4*)&w[4*t4] = *(const float4*)&W2p[(size_t)(k+r)*OC + 4*t4];
      #pragma unroll
      for(int g=0;g<G;g++){
        const float sx = ((const float*)&sv[g])[r];
        #pragma unroll
        for(int t=0;t<OT;t++) accg[g][t] += sx*w[t];
      }
    }
  }
  // b2 term via xbar (split 0 only)
  if(split==0){
    #pragma unroll
    for(int j=0;j<TI;j++){
      const int i = kc + 16*j;
      float w[OT];
      #pragma unroll
      for(int t4=0;t4<OT/4;t4++)
        *(float4*)&w[4*t4] = *(const float4*)&b2[(size_t)i*OC + o0 + 4*t4];
      #pragma unroll
      for(int g=0;g<G;g++){
        const float xb = xbs[(wid*G+g)*IC + i];
        #pragma unroll
        for(int t=0;t<OT;t++) accg[g][t] += xb*w[t];
      }
    }
  }
  // reduce over the 16 kc-lanes
  #pragma unroll
  for(int mask=1; mask<16; mask<<=1)
    #pragma unroll
    for(int g=0;g<G;g++)
      #pragma unroll
      for(int t=0;t<OT;t++) accg[g][t] += __shfl_xor(accg[g][t], mask, 64);
  if(kc==0){
    #pragma unroll
    for(int g=0;g<G;g++)
      #pragma unroll
      for(int t4=0;t4<OT/4;t4++){
        float4 v = make_float4(accg[g][4*t4], accg[g][4*t4+1], accg[g][4*t4+2], accg[g][4*t4+3]);
        *(float4*)&part[((size_t)split*NN + nodeBase+g)*OC + o0 + 4*t4] = v;
      }
  }
}

// ---------------- epilogue: y = relu(sum_s part[s] + x@root + bias) ----------------
template<int IC, int OC, int KS>
__global__ void k_epi(const float* __restrict__ part, const float* __restrict__ x,
                      const float* __restrict__ root, const float* __restrict__ bias,
                      float* __restrict__ y)
{
  int idx = blockIdx.x*256 + threadIdx.x;
  if(idx >= NN*OC) return;
  int n = idx/OC, o = idx - n*OC;
  float v = bias[o];
  #pragma unroll
  for(int s=0;s<KS;s++) v += part[(size_t)s*NN*OC + idx];
  #pragma unroll
  for(int i=0;i<IC;i++) v += x[(size_t)n*IC+i]*root[i*OC+o];
  y[idx] = fmaxf(v, 0.f);
}

// ---------------- set2set (2 steps) + final MLP, one wave per graph ----------------
__global__ void k_s2s(const float* __restrict__ xg, const int* __restrict__ batch,
  const float* __restrict__ Wih, const float* __restrict__ Whh,
  const float* __restrict__ bih, const float* __restrict__ bhh,
  const float* __restrict__ l1W, const float* __restrict__ l1b,
  const float* __restrict__ l2W, const float* __restrict__ l2b,
  const float* __restrict__ lfW, const float* __restrict__ lfb,
  float* __restrict__ out)
{
  int g = blockIdx.x, lane = threadIdx.x;
  __shared__ float hs[16], cs[16], qs[32], gs[64], rs[16];
  int r0 = lowerb(batch, NN, g);
  int r1 = lowerb(batch, NN, g+1);
  if(lane<16){ hs[lane]=0.f; cs[lane]=0.f; }
  if(lane<32) qs[lane]=0.f;
  __syncthreads();
  for(int step=0; step<2; step++){
    float gate = bih[lane] + bhh[lane];
    for(int k=0;k<32;k++) gate += qs[k]*Wih[lane*32+k];
    for(int k=0;k<16;k++) gate += hs[k]*Whh[lane*16+k];
    gs[lane] = gate;
    __syncthreads();
    if(lane<16){
      float ig = 1.f/(1.f+expf(-gs[lane]));
      float fg = 1.f/(1.f+expf(-gs[lane+16]));
      float gg = tanhf(gs[lane+32]);
      float og = 1.f/(1.f+expf(-gs[lane+48]));
      float cn = fg*cs[lane] + ig*gg;
      cs[lane] = cn;
      hs[lane] = og*tanhf(cn);
    }
    __syncthreads();
    float m = -1e30f;
    for(int n=r0+lane; n<r1; n+=64){
      float e=0.f;
      for(int k=0;k<16;k++) e += xg[n*16+k]*hs[k];
      m = fmaxf(m, e);
    }
    for(int d=1; d<64; d<<=1) m = fmaxf(m, __shfl_xor(m, d));
    float ssum = 0.f;
    float racc[16];
    #pragma unroll
    for(int k=0;k<16;k++) racc[k]=0.f;
    for(int n=r0+lane; n<r1; n+=64){
      float e=0.f, xv[16];
      #pragma unroll
      for(int k=0;k<16;k++){ xv[k]=xg[n*16+k]; e += xv[k]*hs[k]; }
      float a = expf(e - m);
      ssum += a;
      #pragma unroll
      for(int k=0;k<16;k++) racc[k] += a*xv[k];
    }
    for(int d=1; d<64; d<<=1) ssum += __shfl_xor(ssum, d);
    #pragma unroll
    for(int k=0;k<16;k++)
      for(int d=1; d<64; d<<=1) racc[k] += __shfl_xor(racc[k], d);
    ssum = fmaxf(ssum, 1e-16f);
    if(lane==0){
      #pragma unroll
      for(int k=0;k<16;k++) rs[k] = racc[k]/ssum;
    }
    __syncthreads();
    if(lane<16){ qs[lane]=hs[lane]; qs[16+lane]=rs[lane]; }
    __syncthreads();
  }
  if(lane<16){
    float v = l1b[lane];
    for(int k=0;k<32;k++) v += qs[k]*l1W[k*16+lane];
    gs[lane] = fmaxf(v,0.f);
  }
  __syncthreads();
  if(lane<8){
    float v = l2b[lane];
    for(int k=0;k<16;k++) v += gs[k]*l2W[k*8+lane];
    gs[32+lane] = fmaxf(v,0.f);
  }
  __syncthreads();
  if(lane==0){
    float v = lfb[0];
    for(int k=0;k<8;k++) v += gs[32+k]*lfW[k];
    out[g] = v;
  }
}

extern "C" void kernel_launch(void* const* d_in, const int* in_sizes, int n_in,
                              void* d_out, int out_size, void* d_ws, size_t ws_size,
                              hipStream_t stream) {
  const float* x0   = (const float*)d_in[0];
  const int*   ei   = (const int*)d_in[1];
  const float* ea   = (const float*)d_in[2];
  const int*   batch= (const int*)d_in[3];
  const float* c1W1 = (const float*)d_in[4];  const float* c1b1 = (const float*)d_in[5];
  const float* c1W2 = (const float*)d_in[6];  const float* c1b2 = (const float*)d_in[7];
  const float* c1rt = (const float*)d_in[8];  const float* c1bs = (const float*)d_in[9];
  const float* c2W1 = (const float*)d_in[10]; const float* c2b1 = (const float*)d_in[11];
  const float* c2W2 = (const float*)d_in[12]; const float* c2b2 = (const float*)d_in[13];
  const float* c2rt = (const float*)d_in[14]; const float* c2bs = (const float*)d_in[15];
  const float* c3W1 = (const float*)d_in[16]; const float* c3b1 = (const float*)d_in[17];
  const float* c3W2 = (const float*)d_in[18]; const float* c3b2 = (const float*)d_in[19];
  const float* c3rt = (const float*)d_in[20]; const float* c3bs = (const float*)d_in[21];
  const float* Wih  = (const float*)d_in[22]; const float* Whh  = (const float*)d_in[23];
  const float* bih  = (const float*)d_in[24]; const float* bhh  = (const float*)d_in[25];
  const float* l1W  = (const float*)d_in[26]; const float* l1b  = (const float*)d_in[27];
  const float* l2W  = (const float*)d_in[28]; const float* l2b  = (const float*)d_in[29];
  const float* lfW  = (const float*)d_in[30]; const float* lfb  = (const float*)d_in[31];
  float* out = (float*)d_out;

  const int* src = ei;
  const int* tgt = ei + NE;

  // workspace carve (~178 MB)
  char* w = (char*)d_ws;
  auto carve = [&](size_t bytes)->void*{ void* p = (void*)w; w += (bytes + 255) & ~(size_t)255; return p; };
  int*   row_start = (int*)carve((NN+1)*sizeof(int));
  int*   cur       = (int*)carve(NN*sizeof(int));
  int*   es_src    = (int*)carve(NE*sizeof(int));
  int*   es_pos    = (int*)carve(NE*sizeof(int));
  float* es_ea     = (float*)carve((size_t)NE*16*sizeof(float));
  float* Hbuf      = (float*)carve((size_t)NE*128*sizeof(float));
  float* xg        = (float*)carve((size_t)NE*48*sizeof(float));
  float* y1   = (float*)carve((size_t)NN*48*sizeof(float));
  float* y2   = (float*)carve((size_t)NN*32*sizeof(float));
  float* y3   = (float*)carve((size_t)NN*16*sizeof(float));
  float* part = (float*)carve((size_t)4*NN*48*sizeof(float));

  // ---- CSR by tgt + ea gather
  hipMemsetAsync(cur, 0, NN*sizeof(int), stream);
  k_count<<<(NE+255)/256, 256, 0, stream>>>(tgt, cur);
  k_scan<<<1, 1024, 0, stream>>>(cur, row_start);
  hipMemsetAsync(cur, 0, NN*sizeof(int), stream);
  k_place<<<(NE+255)/256, 256, 0, stream>>>(src, tgt, row_start, cur, es_src, es_pos);
  k_gatherea<<<(NE+255)/256, 256, 0, stream>>>(ea, es_pos, es_ea);

  // ---- layer 1: IC=16 OC=48, BN=16 (G=4), KS=4
  k_gatherx<16><<<NE*4/256, 256, 0, stream>>>(x0, es_src, xg);
  k_hmlp<<<NE/8, 256, 0, stream>>>(es_ea, c1W1, c1b1, Hbuf);
  k_layer<16,48,4,16,4><<<(NN/16)*4, 256, 0, stream>>>(xg, Hbuf, row_start, c1W2, c1b2, part);
  k_epi<16,48,4><<<(NN*48+255)/256, 256, 0, stream>>>(part, x0, c1rt, c1bs, y1);

  // ---- layer 2: IC=48 OC=32, BN=8 (G=2), KS=4
  k_gatherx<48><<<NE*12/256, 256, 0, stream>>>(y1, es_src, xg);
  k_hmlp<<<NE/8, 256, 0, stream>>>(es_ea, c2W1, c2b1, Hbuf);
  k_layer<48,32,4,8,3><<<(NN/8)*4, 256, 0, stream>>>(xg, Hbuf, row_start, c2W2, c2b2, part);
  k_epi<48,32,4><<<(NN*32+255)/256, 256, 0, stream>>>(part, y1, c2rt, c2bs, y2);

  // ---- layer 3: IC=32 OC=16, BN=8 (G=2), KS=4
  k_gatherx<32><<<NE*8/256, 256, 0, stream>>>(y2, es_src, xg);
  k_hmlp<<<NE/8, 256, 0, stream>>>(es_ea, c3W1, c3b1, Hbuf);
  k_layer<32,16,4,8,4><<<(NN/8)*4, 256, 0, stream>>>(xg, Hbuf, row_start, c3W2, c3b2, part);
  k_epi<32,16,4><<<(NN*16+255)/256, 256, 0, stream>>>(part, y2, c3rt, c3bs, y3);

  // ---- set2set + MLP head
  k_s2s<<<NG, 64, 0, stream>>>(y3, batch, Wih, Whh, bih, bhh, l1W, l1b, l2W, l2b, lfW, lfb, out);
}